// Round 2
// baseline (78.936 us; speedup 1.0000x reference)
//
#include <hip/hip_runtime.h>
#include <hip/hip_bf16.h>
#include <stdint.h>

#define NB   16
#define CIN  2048
#define OUTC 256
#define HW   1024
#define BJ   32
#define BK   32
#define NJT  (HW / BJ)          // 32 j-tiles
#define KSTEPS (CIN / BK)       // 64
#define APAD 40                 // padded LDS row (32 payload + 8 pad shorts; 80 B)

typedef __attribute__((ext_vector_type(8))) short bf16x8;
typedef __attribute__((ext_vector_type(4))) float f32x4;
typedef __attribute__((ext_vector_type(4))) unsigned int u32x4;

__device__ __forceinline__ unsigned int f2bf(float f) {
    union { float f; unsigned int u; } a; a.f = f;
    return (a.u + 0x7FFFu + ((a.u >> 16) & 1u)) >> 16;  // RNE
}

// ---- kernel 1: W fp32 -> bf16 (1 MiB, L2-resident for the GEMM) ----
__global__ void wconv_kernel(const float* __restrict__ W, unsigned short* __restrict__ W16) {
    int i = (blockIdx.x * blockDim.x + threadIdx.x) * 4;
    float4 v = *reinterpret_cast<const float4*>(W + i);
    ushort4 o;
    o.x = (unsigned short)f2bf(v.x);
    o.y = (unsigned short)f2bf(v.y);
    o.z = (unsigned short)f2bf(v.z);
    o.w = (unsigned short)f2bf(v.w);
    *reinterpret_cast<ushort4*>(W16 + i) = o;
}

// ---- kernel 2: per-batch GEMM y = W x_n, reduced in-register to
//      s1_part[jt][n][o] and s2_part[blk][o]. BM=256 (x read exactly once),
//      BN=32 -> grid 512 = 2 blocks/CU for TLP latency hiding.
__global__ __launch_bounds__(512, 4) void gemm_stats_kernel(
    const float* __restrict__ x,             // [16][2048][1024]
    const unsigned short* __restrict__ W16,  // [256][2048] bf16
    float* __restrict__ s1_part,             // [NJT][NB][OUTC]
    float* __restrict__ s2_part)             // [NB*NJT][OUTC]
{
    __shared__ __align__(16) unsigned short Asm[256][APAD]; // [o][k], 20 KB
    __shared__ __align__(16) unsigned short Bsm[BJ][APAD];  // [j][k], 2.5 KB

    const int tid  = threadIdx.x;
    const int lane = tid & 63;
    const int wave = tid >> 6;     // 0..7, wave's o-rows = [32w, 32w+32)
    const int blk  = blockIdx.x;   // 0..511
    const int n    = blk >> 5;
    const int jt   = blk & 31;
    const int j0   = jt * BJ;

    const float* xn = x + (size_t)n * CIN * HW;

    // A staging: thread -> (row = tid>>1, half = tid&1): 16 bf16 = 2x 16B loads
    const int arow  = tid >> 1;
    const int ahalf = tid & 1;
    const unsigned short* Ag = W16 + arow * CIN + ahalf * 16;

    // B staging: thread -> (j = tid&31, q = tid>>5 in 0..15): rows c = 2q, 2q+1
    const int bj = tid & 31;
    const int bq = tid >> 5;
    const float* Bg = xn + (size_t)(bq * 2) * HW + j0 + bj;

    // prefetch K-step 0 into registers
    u32x4 a0 = *(const u32x4*)(Ag);
    u32x4 a1 = *(const u32x4*)(Ag + 8);
    float b0 = Bg[0], b1 = Bg[HW];

    f32x4 acc[2][2] = {};

    const int rA   = lane & 15;   // fragment row/col index
    const int gK   = lane >> 4;   // k-group
    const int aoff = gK * 8;

    for (int ks = 0; ks < KSTEPS; ++ks) {
        __syncthreads();                       // prev step's LDS reads complete
        *(u32x4*)&Asm[arow][ahalf * 16]     = a0;
        *(u32x4*)&Asm[arow][ahalf * 16 + 8] = a1;
        *(unsigned int*)&Bsm[bj][bq * 2] = f2bf(b0) | (f2bf(b1) << 16);
        if (ks + 1 < KSTEPS) {                 // next step's loads fly during MFMA
            const unsigned short* Ag2 = Ag + (ks + 1) * BK;
            a0 = *(const u32x4*)(Ag2);
            a1 = *(const u32x4*)(Ag2 + 8);
            const float* Bg2 = Bg + (size_t)(ks + 1) * BK * HW;
            b0 = Bg2[0]; b1 = Bg2[HW];
        }
        __syncthreads();                       // staged data visible

        bf16x8 af0 = *(const bf16x8*)&Asm[wave * 32 + rA][aoff];
        bf16x8 af1 = *(const bf16x8*)&Asm[wave * 32 + 16 + rA][aoff];
        bf16x8 bf0 = *(const bf16x8*)&Bsm[rA][aoff];
        bf16x8 bf1 = *(const bf16x8*)&Bsm[16 + rA][aoff];
        acc[0][0] = __builtin_amdgcn_mfma_f32_16x16x32_bf16(af0, bf0, acc[0][0], 0, 0, 0);
        acc[1][0] = __builtin_amdgcn_mfma_f32_16x16x32_bf16(af1, bf0, acc[1][0], 0, 0, 0);
        acc[0][1] = __builtin_amdgcn_mfma_f32_16x16x32_bf16(af0, bf1, acc[0][1], 0, 0, 0);
        acc[1][1] = __builtin_amdgcn_mfma_f32_16x16x32_bf16(af1, bf1, acc[1][1], 0, 0, 0);
    }

    // ---- epilogue: per-channel sum / sum-of-squares over this block's 32 j ----
    // C/D layout: col(j) = lane&15, row = (lane>>4)*4 + r  [m89]
    float rs[2][4], rq[2][4];
    #pragma unroll
    for (int mi = 0; mi < 2; ++mi) {
        #pragma unroll
        for (int r = 0; r < 4; ++r) {
            float v0 = acc[mi][0][r], v1 = acc[mi][1][r];
            rs[mi][r] = v0 + v1;
            rq[mi][r] = v0 * v0 + v1 * v1;
        }
    }
    #pragma unroll
    for (int m = 1; m < 16; m <<= 1) {         // reduce across 16 j-lanes
        #pragma unroll
        for (int mi = 0; mi < 2; ++mi) {
            #pragma unroll
            for (int r = 0; r < 4; ++r) {
                rs[mi][r] += __shfl_xor(rs[mi][r], m, 64);
                rq[mi][r] += __shfl_xor(rq[mi][r], m, 64);
            }
        }
    }
    if (rA == 0) {
        #pragma unroll
        for (int mi = 0; mi < 2; ++mi) {
            #pragma unroll
            for (int r = 0; r < 4; ++r) {
                int o = wave * 32 + mi * 16 + gK * 4 + r;
                s1_part[(jt * NB + n) * OUTC + o] = rs[mi][r];
                s2_part[blk * OUTC + o]           = rq[mi][r];
            }
        }
    }
}

// ---- kernel 3 (fused finalize+broadcast): each block = (n, 16 channels).
//      Redundantly reduces the L2-resident partials (stats identical across n),
//      then writes its 16x1024-float broadcast slab. Deterministic, no atomics.
__global__ __launch_bounds__(256) void finalize_bcast_kernel(
    const float* __restrict__ s1_part,   // [NJT][NB][OUTC]
    const float* __restrict__ s2_part,   // [NB*NJT][OUTC]
    const float* __restrict__ gamma,
    const float* __restrict__ beta,
    float* __restrict__ out)             // [NB][OUTC][1024]
{
    const int tid   = threadIdx.x;
    const int slice = tid & 15;          // contiguous lanes -> shfl reduce
    const int o_l   = tid >> 4;
    const int n0    = blockIdx.x >> 4;
    const int o     = (blockIdx.x & 15) * 16 + o_l;

    float S1 = 0.f, S2 = 0.f;
    #pragma unroll
    for (int q = 0; q < 32; ++q) {
        int p = slice * 32 + q;          // covers all 512 partials
        S1 += s1_part[p * OUTC + o];
        S2 += s2_part[p * OUTC + o];
    }
    // this block's n: s1n = sum over t of s1_part[t][n0][o]
    float s1n = s1_part[(slice * 2 * NB + n0) * OUTC + o]
              + s1_part[((slice * 2 + 1) * NB + n0) * OUTC + o];
    #pragma unroll
    for (int m = 1; m < 16; m <<= 1) {
        S1  += __shfl_xor(S1, m, 64);
        S2  += __shfl_xor(S2, m, 64);
        s1n += __shfl_xor(s1n, m, 64);
    }
    float mean = S1 * (1.f / 16384.f);
    float var  = S2 * (1.f / 16384.f) - mean * mean;   // biased var (matches ref)
    float inv  = rsqrtf(var + 1e-5f);
    float v = gamma[o] * (s1n * (1.f / 1024.f) - mean) * inv + beta[o];

    float4 vv = make_float4(v, v, v, v);
    float4* dst = reinterpret_cast<float4*>(out + ((size_t)(n0 * OUTC + o)) * HW);
    #pragma unroll
    for (int it = 0; it < 16; ++it)
        dst[it * 16 + slice] = vv;
}

extern "C" void kernel_launch(void* const* d_in, const int* in_sizes, int n_in,
                              void* d_out, int out_size, void* d_ws, size_t ws_size,
                              hipStream_t stream) {
    const float* x     = (const float*)d_in[0];
    const float* W     = (const float*)d_in[1];
    const float* gamma = (const float*)d_in[2];
    const float* beta  = (const float*)d_in[3];
    float* out = (float*)d_out;

    char* ws = (char*)d_ws;
    unsigned short* W16 = (unsigned short*)ws;                   // 1 MiB
    float* s1_part = (float*)(ws + (1 << 20));                   // 512 KB
    float* s2_part = (float*)(ws + (1 << 20) + (512 << 10));     // 512 KB

    hipLaunchKernelGGL(wconv_kernel, dim3(512), dim3(256), 0, stream, W, W16);
    hipLaunchKernelGGL(gemm_stats_kernel, dim3(NB * NJT), dim3(512), 0, stream,
                       x, W16, s1_part, s2_part);
    hipLaunchKernelGGL(finalize_bcast_kernel, dim3(NB * (OUTC / 16)), dim3(256), 0, stream,
                       s1_part, s2_part, gamma, beta, out);
}

// Round 3
// 56.023 us; speedup vs baseline: 1.4090x; 1.4090x over previous
//
#include <hip/hip_runtime.h>
#include <hip/hip_bf16.h>
#include <stdint.h>

#define NB   16
#define CIN  2048
#define OUTC 256
#define HW   1024
#define BJ   64
#define BK   32
#define NJT  (HW / BJ)          // 16 j-tiles
#define KSTEPS (CIN / BK)       // 64

typedef __attribute__((ext_vector_type(8))) short bf16x8;
typedef __attribute__((ext_vector_type(4))) float f32x4;
typedef __attribute__((ext_vector_type(4))) unsigned int u32x4;

__device__ __forceinline__ unsigned int f2bf(float f) {
    union { float f; unsigned int u; } a; a.f = f;
    return (a.u + 0x7FFFu + ((a.u >> 16) & 1u)) >> 16;  // RNE
}

// Raw barrier: drains LDS ops only; global prefetch loads stay in flight
// (rule #18-adjacent: memory-clobber asm pins store/load program order; the
// trailing empty asm keeps next iter's ds_reads from hoisting above).
__device__ __forceinline__ void block_sync_lds() {
    asm volatile("s_waitcnt lgkmcnt(0)" ::: "memory");
    __builtin_amdgcn_s_barrier();
    asm volatile("" ::: "memory");
}

// ---- kernel 1: W fp32 -> bf16 (1 MiB, L2-resident for the GEMM) ----
__global__ void wconv_kernel(const float* __restrict__ W, unsigned short* __restrict__ W16) {
    int i = (blockIdx.x * blockDim.x + threadIdx.x) * 4;
    float4 v = *reinterpret_cast<const float4*>(W + i);
    ushort4 o;
    o.x = (unsigned short)f2bf(v.x);
    o.y = (unsigned short)f2bf(v.y);
    o.z = (unsigned short)f2bf(v.z);
    o.w = (unsigned short)f2bf(v.w);
    *reinterpret_cast<ushort4*>(W16 + i) = o;
}

// ---- kernel 2: per-batch GEMM, raw-barrier pipelined, fragment-linear LDS.
//      LDS layout (shorts): [otile][rA][g ^ (rA&3)][8] -> wave fragment reads
//      are a perfect 64-slot permutation (conflict-free).
__global__ __launch_bounds__(512, 2) void gemm_stats_kernel(
    const float* __restrict__ x,             // [16][2048][1024]
    const unsigned short* __restrict__ W16,  // [256][2048] bf16
    float* __restrict__ s1_part,             // [NJT][NB][OUTC]
    float* __restrict__ s2_part)             // [256][OUTC]
{
    __shared__ __align__(16) unsigned short A0[8192], A1[8192]; // 16 KB each
    __shared__ __align__(16) unsigned short B0[2048], B1[2048]; // 4 KB each

    const int tid  = threadIdx.x;
    const int lane = tid & 63;
    const int wave = tid >> 6;
    const int blk  = blockIdx.x;   // 0..255
    const int n    = blk >> 4;
    const int jt   = blk & 15;
    const int j0   = jt * BJ;

    const float* xn = x + (size_t)n * CIN * HW;

    // A staging: thread -> (row = tid>>1, half = tid&1), 2x16B chunks (g = 2*half+c)
    const int arow  = tid >> 1;
    const int ahalf = tid & 1;
    const unsigned short* Agp = W16 + arow * CIN + ahalf * 16;
    const int offA0 = (arow >> 4) * 512 + (arow & 15) * 32 + ((2 * ahalf + 0) ^ (arow & 3)) * 8;
    const int offA1 = (arow >> 4) * 512 + (arow & 15) * 32 + ((2 * ahalf + 1) ^ (arow & 3)) * 8;

    // B staging: thread -> (j = tid&63, kh = tid>>6): 4 floats k = kh*4+i
    const int bj = tid & 63;
    const int kh = tid >> 6;
    const float* Bgp = xn + (size_t)(kh * 4) * HW + j0 + bj;
    const int offB = (bj >> 4) * 512 + (bj & 15) * 32 + (((kh >> 1)) ^ (bj & 3)) * 8 + (kh & 1) * 4;

    // fragment read offsets (shorts)
    const int rA = lane & 15;
    const int gX = (lane >> 4) ^ (rA & 3);
    const int roffA0 = (2 * wave) * 512 + rA * 32 + gX * 8;
    const int roffA1 = (2 * wave + 1) * 512 + rA * 32 + gX * 8;
    const int roffB  = rA * 32 + gX * 8;   // + ni*512

#define LDA(ks, r0, r1) { r0 = *(const u32x4*)(Agp + (ks) * BK); \
                          r1 = *(const u32x4*)(Agp + (ks) * BK + 8); }
#define LDB(ks, f0, f1, f2, f3) { const float* p = Bgp + (size_t)(ks) * BK * HW; \
                                  f0 = p[0]; f1 = p[HW]; f2 = p[2 * HW]; f3 = p[3 * HW]; }
#define WRITE(Ab, Bb, r0, r1, f0, f1, f2, f3) { \
    *(u32x4*)&Ab[offA0] = r0; *(u32x4*)&Ab[offA1] = r1; \
    uint2 pk; pk.x = f2bf(f0) | (f2bf(f1) << 16); pk.y = f2bf(f2) | (f2bf(f3) << 16); \
    *(uint2*)&Bb[offB] = pk; }
#define COMPUTE(Ab, Bb) { \
    bf16x8 af0 = *(const bf16x8*)&Ab[roffA0]; \
    bf16x8 af1 = *(const bf16x8*)&Ab[roffA1]; \
    _Pragma("unroll") \
    for (int ni = 0; ni < 4; ++ni) { \
        bf16x8 bf = *(const bf16x8*)&Bb[ni * 512 + roffB]; \
        acc[0][ni] = __builtin_amdgcn_mfma_f32_16x16x32_bf16(af0, bf, acc[0][ni], 0, 0, 0); \
        acc[1][ni] = __builtin_amdgcn_mfma_f32_16x16x32_bf16(af1, bf, acc[1][ni], 0, 0, 0); \
    } }

    f32x4 acc[2][4] = {};
    u32x4 a00, a01, a10, a11;
    float b00, b01, b02, b03, b10, b11, b12, b13;

    // prologue: set0 <- L(0), set1 <- L(1); write step0; set0 <- L(2)
    LDA(0, a00, a01); LDB(0, b00, b01, b02, b03);
    LDA(1, a10, a11); LDB(1, b10, b11, b12, b13);
    WRITE(A0, B0, a00, a01, b00, b01, b02, b03);
    LDA(2, a00, a01); LDB(2, b00, b01, b02, b03);
    block_sync_lds();

    #pragma unroll 1
    for (int ks = 0; ks < KSTEPS; ks += 2) {
        COMPUTE(A0, B0);                       // step ks
        {   // write ks+1 (set1), issue ks+3 -> set1
            WRITE(A1, B1, a10, a11, b10, b11, b12, b13);
            int kp = (ks + 3 < KSTEPS) ? ks + 3 : KSTEPS - 1;
            LDA(kp, a10, a11); LDB(kp, b10, b11, b12, b13);
            block_sync_lds();
        }
        COMPUTE(A1, B1);                       // step ks+1
        if (ks + 1 < KSTEPS - 1) {             // write ks+2 (set0), issue ks+4 -> set0
            WRITE(A0, B0, a00, a01, b00, b01, b02, b03);
            int kp = (ks + 4 < KSTEPS) ? ks + 4 : KSTEPS - 1;
            LDA(kp, a00, a01); LDB(kp, b00, b01, b02, b03);
            block_sync_lds();
        }
    }

    // ---- epilogue: per-channel sum / sum-of-squares over this block's 64 j ----
    // C/D layout: col(j) = lane&15, row = (lane>>4)*4 + r  [m89]
    float rs[2][4], rq[2][4];
    #pragma unroll
    for (int mi = 0; mi < 2; ++mi) {
        #pragma unroll
        for (int r = 0; r < 4; ++r) {
            float s = 0.f, q = 0.f;
            #pragma unroll
            for (int ni = 0; ni < 4; ++ni) {
                float v = acc[mi][ni][r];
                s += v; q += v * v;
            }
            rs[mi][r] = s; rq[mi][r] = q;
        }
    }
    #pragma unroll
    for (int m = 1; m < 16; m <<= 1) {
        #pragma unroll
        for (int mi = 0; mi < 2; ++mi) {
            #pragma unroll
            for (int r = 0; r < 4; ++r) {
                rs[mi][r] += __shfl_xor(rs[mi][r], m, 64);
                rq[mi][r] += __shfl_xor(rq[mi][r], m, 64);
            }
        }
    }
    if (rA == 0) {
        const int gK = lane >> 4;
        #pragma unroll
        for (int mi = 0; mi < 2; ++mi) {
            #pragma unroll
            for (int r = 0; r < 4; ++r) {
                int o = wave * 32 + mi * 16 + gK * 4 + r;
                s1_part[(jt * NB + n) * OUTC + o] = rs[mi][r];
                s2_part[blk * OUTC + o]           = rq[mi][r];
            }
        }
    }
#undef LDA
#undef LDB
#undef WRITE
#undef COMPUTE
}

// ---- kernel 3 (fused finalize+broadcast): block = (n, 16 channels).
__global__ __launch_bounds__(256) void finalize_bcast_kernel(
    const float* __restrict__ s1_part,   // [NJT][NB][OUTC]
    const float* __restrict__ s2_part,   // [256][OUTC]
    const float* __restrict__ gamma,
    const float* __restrict__ beta,
    float* __restrict__ out)             // [NB][OUTC][1024]
{
    const int tid   = threadIdx.x;
    const int slice = tid & 15;
    const int o_l   = tid >> 4;
    const int n0    = blockIdx.x >> 4;
    const int o     = (blockIdx.x & 15) * 16 + o_l;

    float S1 = 0.f, S2 = 0.f;
    #pragma unroll
    for (int q = 0; q < 16; ++q) {
        int p = slice * 16 + q;          // covers all 256 partials
        S1 += s1_part[p * OUTC + o];
        S2 += s2_part[p * OUTC + o];
    }
    float s1n = s1_part[(slice * NB + n0) * OUTC + o];   // jt = slice
    #pragma unroll
    for (int m = 1; m < 16; m <<= 1) {
        S1  += __shfl_xor(S1, m, 64);
        S2  += __shfl_xor(S2, m, 64);
        s1n += __shfl_xor(s1n, m, 64);
    }
    float mean = S1 * (1.f / 16384.f);
    float var  = S2 * (1.f / 16384.f) - mean * mean;   // biased var (matches ref)
    float inv  = rsqrtf(var + 1e-5f);
    float v = gamma[o] * (s1n * (1.f / 1024.f) - mean) * inv + beta[o];

    float4 vv = make_float4(v, v, v, v);
    float4* dst = reinterpret_cast<float4*>(out + ((size_t)(n0 * OUTC + o)) * HW);
    #pragma unroll
    for (int it = 0; it < 16; ++it)
        dst[it * 16 + slice] = vv;
}

extern "C" void kernel_launch(void* const* d_in, const int* in_sizes, int n_in,
                              void* d_out, int out_size, void* d_ws, size_t ws_size,
                              hipStream_t stream) {
    const float* x     = (const float*)d_in[0];
    const float* W     = (const float*)d_in[1];
    const float* gamma = (const float*)d_in[2];
    const float* beta  = (const float*)d_in[3];
    float* out = (float*)d_out;

    char* ws = (char*)d_ws;
    unsigned short* W16 = (unsigned short*)ws;                   // 1 MiB
    float* s1_part = (float*)(ws + (1 << 20));                   // 256 KB
    float* s2_part = (float*)(ws + (1 << 20) + (256 << 10));     // 256 KB

    hipLaunchKernelGGL(wconv_kernel, dim3(512), dim3(256), 0, stream, W, W16);
    hipLaunchKernelGGL(gemm_stats_kernel, dim3(256), dim3(512), 0, stream,
                       x, W16, s1_part, s2_part);
    hipLaunchKernelGGL(finalize_bcast_kernel, dim3(NB * (OUTC / 16)), dim3(256), 0, stream,
                       s1_part, s2_part, gamma, beta, out);
}

// Round 4
// 49.152 us; speedup vs baseline: 1.6059x; 1.1398x over previous
//
#include <hip/hip_runtime.h>
#include <hip/hip_bf16.h>
#include <stdint.h>

#define NB   16
#define CIN  2048
#define OUTC 256
#define HW   1024
#define BJ   64
#define BK   64
#define NJT  (HW / BJ)          // 16 j-tiles
#define KSTEPS (CIN / BK)       // 32 steps of 64 k

typedef __attribute__((ext_vector_type(8))) short bf16x8;
typedef __attribute__((ext_vector_type(4))) float f32x4;
typedef __attribute__((ext_vector_type(4))) unsigned int u32x4;

__device__ __forceinline__ unsigned int f2bf(float f) {
    union { float f; unsigned int u; } a; a.f = f;
    return (a.u + 0x7FFFu + ((a.u >> 16) & 1u)) >> 16;  // RNE
}

// Raw barrier: drains LDS ops only; global prefetch loads stay in flight.
__device__ __forceinline__ void block_sync_lds() {
    asm volatile("s_waitcnt lgkmcnt(0)" ::: "memory");
    __builtin_amdgcn_s_barrier();
    asm volatile("" ::: "memory");
}

// ---- kernel 1: W fp32 -> bf16 A-fragments in MFMA lane order.
//      Afrag[ks32][ot][lane][8 bf16]: lane l of fragment (ks32, ot) holds
//      A[row = ot*16 + (l&15)][k = ks32*32 + (l>>4)*8 + i]  (m89 layout).
__global__ void wprep_kernel(const float* __restrict__ W, unsigned short* __restrict__ Afrag) {
    int g  = blockIdx.x * blockDim.x + threadIdx.x;   // 65536
    int o  = g >> 8;           // 0..255
    int kc = g & 255;          // 8-k chunk within row
    const float4* p = reinterpret_cast<const float4*>(W + o * CIN + kc * 8);
    float4 v0 = p[0], v1 = p[1];
    u32x4 pk;
    pk.x = f2bf(v0.x) | (f2bf(v0.y) << 16);
    pk.y = f2bf(v0.z) | (f2bf(v0.w) << 16);
    pk.z = f2bf(v1.x) | (f2bf(v1.y) << 16);
    pk.w = f2bf(v1.z) | (f2bf(v1.w) << 16);
    int ks32 = kc >> 2, g8 = kc & 3;
    int lane = g8 * 16 + (o & 15), ot = o >> 4;
    *reinterpret_cast<u32x4*>(Afrag + (((size_t)ks32 * 16 + ot) * 64 + lane) * 8) = pk;
}

// ---- kernel 2: per-batch GEMM, B-only LDS (swizzled), A direct from L2.
__global__ __launch_bounds__(512, 2) void gemm_stats_kernel(
    const float* __restrict__ x,             // [16][2048][1024]
    const unsigned short* __restrict__ Afrag,
    float* __restrict__ s1_part,             // [NJT][NB][OUTC]
    float* __restrict__ s2_part)             // [256][OUTC]
{
    __shared__ __align__(16) unsigned short B0[4096], B1[4096]; // 8 KB each (64j x 64k)

    const int tid  = threadIdx.x;
    const int lane = tid & 63;
    const int wave = tid >> 6;
    const int blk  = blockIdx.x;   // 0..255
    const int n    = blk >> 4;
    const int jt   = blk & 15;
    const int j0   = jt * BJ;

    const float* xn = x + (size_t)n * CIN * HW;

    // B staging: thread (bj = tid&63, kh = tid>>6 in 0..7) loads 8 floats
    // k = kh*8+i -> one ds_write_b128 at fragment-linear swizzled slot.
    const int bj = tid & 63;
    const int kh = tid >> 6;
    const float* Bgp = xn + (size_t)(kh * 8) * HW + j0 + bj;
    const int offB = (kh >> 2) * 2048 + (bj >> 4) * 512 + (bj & 15) * 32
                   + ((kh & 3) ^ (bj & 3)) * 8;

    // fragment read offsets
    const int rA = lane & 15;
    const int gX = (lane >> 4) ^ (rA & 3);
    const int roffB = rA * 32 + gX * 8;            // + khalf*2048 + ni*512

    // A fragment source: wave-uniform base + lane*16B, 4 frags per 64-k step
    const unsigned short* Ab = Afrag + (size_t)lane * 8;

#define LDA(ks, R) { _Pragma("unroll") \
    for (int h = 0; h < 2; ++h) _Pragma("unroll") for (int t = 0; t < 2; ++t) \
        R[h * 2 + t] = *(const u32x4*)(Ab + ((((ks) * 2 + h) * 16 + 2 * wave + t) * 64) * 8); }
#define LDB(ks, F) { const float* p = Bgp + (size_t)(ks) * BK * HW; \
    _Pragma("unroll") for (int i = 0; i < 8; ++i) F[i] = p[(size_t)i * HW]; }
#define WRITEB(Bb, F) { u32x4 pk; \
    pk.x = f2bf(F[0]) | (f2bf(F[1]) << 16); pk.y = f2bf(F[2]) | (f2bf(F[3]) << 16); \
    pk.z = f2bf(F[4]) | (f2bf(F[5]) << 16); pk.w = f2bf(F[6]) | (f2bf(F[7]) << 16); \
    *(u32x4*)&Bb[offB] = pk; }
#define COMPUTE(Bb, R) { _Pragma("unroll") \
    for (int h = 0; h < 2; ++h) { \
        bf16x8 af0 = *(const bf16x8*)&R[h * 2 + 0]; \
        bf16x8 af1 = *(const bf16x8*)&R[h * 2 + 1]; \
        _Pragma("unroll") \
        for (int ni = 0; ni < 4; ++ni) { \
            bf16x8 bf = *(const bf16x8*)&Bb[h * 2048 + ni * 512 + roffB]; \
            acc[0][ni] = __builtin_amdgcn_mfma_f32_16x16x32_bf16(af0, bf, acc[0][ni], 0, 0, 0); \
            acc[1][ni] = __builtin_amdgcn_mfma_f32_16x16x32_bf16(af1, bf, acc[1][ni], 0, 0, 0); \
    } } }

    f32x4 acc[2][4] = {};
    u32x4 Aa0[4], Aa1[4];
    float Bs0[8], Bs1[8];

    // prologue: A/B for steps 0,1; write B0; reload set0 with step 2
    LDA(0, Aa0); LDB(0, Bs0);
    LDA(1, Aa1); LDB(1, Bs1);
    WRITEB(B0, Bs0);
    LDB(2, Bs0);
    block_sync_lds();

    #pragma unroll 1
    for (int ks = 0; ks < KSTEPS; ks += 2) {
        // ---- step ks (even): compute buf0 / A set0
        COMPUTE(B0, Aa0);
        {
            int ka = (ks + 2 < KSTEPS) ? ks + 2 : KSTEPS - 1;
            LDA(ka, Aa0);                      // refill A set0 (consumed above)
            WRITEB(B1, Bs1);                   // stage data ks+1
            int kb = (ks + 3 < KSTEPS) ? ks + 3 : KSTEPS - 1;
            LDB(kb, Bs1);
            block_sync_lds();
        }
        // ---- step ks+1 (odd): compute buf1 / A set1
        COMPUTE(B1, Aa1);
        if (ks + 2 < KSTEPS) {
            int ka = (ks + 3 < KSTEPS) ? ks + 3 : KSTEPS - 1;
            LDA(ka, Aa1);
            WRITEB(B0, Bs0);                   // stage data ks+2
            int kb = (ks + 4 < KSTEPS) ? ks + 4 : KSTEPS - 1;
            LDB(kb, Bs0);
            block_sync_lds();
        }
    }

    // ---- epilogue: per-channel sum / sum-of-squares over this block's 64 j ----
    // C/D layout: col(j) = lane&15, row = (lane>>4)*4 + r  [m89]
    float rs[2][4], rq[2][4];
    #pragma unroll
    for (int mi = 0; mi < 2; ++mi) {
        #pragma unroll
        for (int r = 0; r < 4; ++r) {
            float s = 0.f, q = 0.f;
            #pragma unroll
            for (int ni = 0; ni < 4; ++ni) {
                float v = acc[mi][ni][r];
                s += v; q += v * v;
            }
            rs[mi][r] = s; rq[mi][r] = q;
        }
    }
    #pragma unroll
    for (int m = 1; m < 16; m <<= 1) {
        #pragma unroll
        for (int mi = 0; mi < 2; ++mi) {
            #pragma unroll
            for (int r = 0; r < 4; ++r) {
                rs[mi][r] += __shfl_xor(rs[mi][r], m, 64);
                rq[mi][r] += __shfl_xor(rq[mi][r], m, 64);
            }
        }
    }
    if (rA == 0) {
        const int gK = lane >> 4;
        #pragma unroll
        for (int mi = 0; mi < 2; ++mi) {
            #pragma unroll
            for (int r = 0; r < 4; ++r) {
                int o = wave * 32 + mi * 16 + gK * 4 + r;
                s1_part[(jt * NB + n) * OUTC + o] = rs[mi][r];
                s2_part[blk * OUTC + o]           = rq[mi][r];
            }
        }
    }
#undef LDA
#undef LDB
#undef WRITEB
#undef COMPUTE
}

// ---- kernel 3 (fused finalize+broadcast): block = (n, 16 channels).
__global__ __launch_bounds__(256) void finalize_bcast_kernel(
    const float* __restrict__ s1_part,   // [NJT][NB][OUTC]
    const float* __restrict__ s2_part,   // [256][OUTC]
    const float* __restrict__ gamma,
    const float* __restrict__ beta,
    float* __restrict__ out)             // [NB][OUTC][1024]
{
    const int tid   = threadIdx.x;
    const int slice = tid & 15;
    const int o_l   = tid >> 4;
    const int n0    = blockIdx.x >> 4;
    const int o     = (blockIdx.x & 15) * 16 + o_l;

    float S1 = 0.f, S2 = 0.f;
    #pragma unroll
    for (int q = 0; q < 16; ++q) {
        int p = slice * 16 + q;          // covers all 256 partials
        S1 += s1_part[p * OUTC + o];
        S2 += s2_part[p * OUTC + o];
    }
    float s1n = s1_part[(slice * NB + n0) * OUTC + o];   // jt = slice
    #pragma unroll
    for (int m = 1; m < 16; m <<= 1) {
        S1  += __shfl_xor(S1, m, 64);
        S2  += __shfl_xor(S2, m, 64);
        s1n += __shfl_xor(s1n, m, 64);
    }
    float mean = S1 * (1.f / 16384.f);
    float var  = S2 * (1.f / 16384.f) - mean * mean;   // biased var (matches ref)
    float inv  = rsqrtf(var + 1e-5f);
    float v = gamma[o] * (s1n * (1.f / 1024.f) - mean) * inv + beta[o];

    float4 vv = make_float4(v, v, v, v);
    float4* dst = reinterpret_cast<float4*>(out + ((size_t)(n0 * OUTC + o)) * HW);
    #pragma unroll
    for (int it = 0; it < 16; ++it)
        dst[it * 16 + slice] = vv;
}

extern "C" void kernel_launch(void* const* d_in, const int* in_sizes, int n_in,
                              void* d_out, int out_size, void* d_ws, size_t ws_size,
                              hipStream_t stream) {
    const float* x     = (const float*)d_in[0];
    const float* W     = (const float*)d_in[1];
    const float* gamma = (const float*)d_in[2];
    const float* beta  = (const float*)d_in[3];
    float* out = (float*)d_out;

    char* ws = (char*)d_ws;
    unsigned short* Afrag = (unsigned short*)ws;                 // 1 MiB
    float* s1_part = (float*)(ws + (1 << 20));                   // 256 KB
    float* s2_part = (float*)(ws + (1 << 20) + (256 << 10));     // 256 KB

    hipLaunchKernelGGL(wprep_kernel, dim3(256), dim3(256), 0, stream, W, Afrag);
    hipLaunchKernelGGL(gemm_stats_kernel, dim3(256), dim3(512), 0, stream,
                       x, Afrag, s1_part, s2_part);
    hipLaunchKernelGGL(finalize_bcast_kernel, dim3(NB * (OUTC / 16)), dim3(256), 0, stream,
                       s1_part, s2_part, gamma, beta, out);
}